// Round 5
// baseline (683.097 us; speedup 1.0000x reference)
//
#include <hip/hip_runtime.h>
#include <math.h>

#define N_NODES 50000
#define N_EDGES 800000
#define ET (N_EDGES + N_NODES)      // 850000 edges incl. self-loops
#define IN_DIM 128
#define HID 64
#define HEADS 4
#define D1 256                      // HID*HEADS
#define NCLS 40
#define NEG_SLOPE 0.2f
#define BN_EPS 1e-5f
#define SM_EPS 1e-16f

typedef unsigned short ushort_t;
typedef __attribute__((ext_vector_type(8))) short short8;
typedef __attribute__((ext_vector_type(16))) float f32x16;

__device__ __forceinline__ float eluf(float x) { return x > 0.f ? x : expm1f(x); }
__device__ __forceinline__ float lrelu(float x) { return x >= 0.f ? x : NEG_SLOPE * x; }
__device__ __forceinline__ unsigned short f2bf(float f) {   // RNE fp32->bf16
    unsigned int u = __float_as_uint(f);
    u += 0x7fffu + ((u >> 16) & 1u);
    return (unsigned short)(u >> 16);
}
__device__ __forceinline__ float bf2f(ushort_t u) {
    return __uint_as_float(((unsigned int)u) << 16);
}

// ---------------------------------------------------------------- CSR build
__global__ void k_deg(const int* __restrict__ ei, int* __restrict__ deg) {
    int e = blockIdx.x * blockDim.x + threadIdx.x;
    if (e >= ET) return;
    int dst = (e < N_EDGES) ? ei[N_EDGES + e] : (e - N_EDGES);
    atomicAdd(&deg[dst], 1);
}

__global__ __launch_bounds__(1024) void k_scan(const int* __restrict__ deg,
                                               int* __restrict__ row_start,
                                               int* __restrict__ cursor) {
    __shared__ int wsum[16];
    __shared__ int chunk_tot;
    __shared__ int carry_sh;
    const int t = threadIdx.x;
    const int w = t >> 6, lane = t & 63;
    if (t == 0) carry_sh = 0;
    __syncthreads();
    for (int base = 0; base < N_NODES; base += 1024) {
        const int idx = base + t;
        int v = (idx < N_NODES) ? deg[idx] : 0;
        int s = v;
        #pragma unroll
        for (int off = 1; off < 64; off <<= 1) {
            int y = __shfl_up(s, off, 64);
            if (lane >= off) s += y;
        }
        if (lane == 63) wsum[w] = s;
        __syncthreads();
        if (t < 16) {
            int x = wsum[t];
            int sc = x;
            #pragma unroll
            for (int off = 1; off < 16; off <<= 1) {
                int y = __shfl_up(sc, off, 64);
                if (t >= off) sc += y;
            }
            wsum[t] = sc - x;
            if (t == 15) chunk_tot = sc;
        }
        __syncthreads();
        const int excl = carry_sh + wsum[w] + (s - v);
        if (idx < N_NODES) { row_start[idx] = excl; cursor[idx] = excl; }
        __syncthreads();
        if (t == 0) carry_sh += chunk_tot;
    }
    __syncthreads();
    if (t == 0) row_start[N_NODES] = carry_sh;
}

__global__ void k_scatter(const int* __restrict__ ei, int* __restrict__ cursor,
                          int* __restrict__ csr_src) {
    int e = blockIdx.x * blockDim.x + threadIdx.x;
    if (e >= ET) return;
    int src, dst;
    if (e < N_EDGES) { src = ei[e]; dst = ei[N_EDGES + e]; }
    else             { src = dst = e - N_EDGES; }
    int pos = atomicAdd(&cursor[dst], 1);
    csr_src[pos] = src;
}

// ---------------------------------------------------------------- converts
__global__ void k_cvt_x(const float* __restrict__ x, ushort_t* __restrict__ xb, int n4) {
    int i = blockIdx.x * blockDim.x + threadIdx.x;
    if (i >= n4) return;
    float4 v = ((const float4*)x)[i];
    ushort4 o;
    o.x = f2bf(v.x); o.y = f2bf(v.y); o.z = f2bf(v.z); o.w = f2bf(v.w);
    ((ushort4*)xb)[i] = o;
}

// BT1[n][k] (512 x 128) = [Wl1 | Wr1]^T  (Wl1, Wr1: 128 x 256)
__global__ void k_cvt_w1(const float* __restrict__ Wl, const float* __restrict__ Wr,
                         ushort_t* __restrict__ BT) {
    int n = blockIdx.x;          // 0..511
    int k = threadIdx.x;         // 0..127
    float v = (n < 256) ? Wl[k * 256 + n] : Wr[k * 256 + (n - 256)];
    BT[n * 128 + k] = f2bf(v);
}

// BT2[n][k] (128 x 256, rows 80..127 zero) = [Wl2 | Wr2]^T  (Wl2, Wr2: 256 x 40)
__global__ void k_cvt_w2(const float* __restrict__ Wl, const float* __restrict__ Wr,
                         ushort_t* __restrict__ BT) {
    int n = blockIdx.x;          // 0..127
    int k = threadIdx.x;         // 0..255
    float v = 0.f;
    if (n < 40)      v = Wl[k * 40 + n];
    else if (n < 80) v = Wr[k * 40 + (n - 40)];
    BT[n * 256 + k] = f2bf(v);
}

// h1b = bf16(elu(bn_g*h1 + bn_b)); 4 elems/thread, 256 cols
__global__ void k_cvt_h(const float* __restrict__ h1, const float* __restrict__ g,
                        const float* __restrict__ b, ushort_t* __restrict__ h1b) {
    int i = blockIdx.x * blockDim.x + threadIdx.x;   // elem-quad index
    int c0 = (threadIdx.x * 4) & 255;
    float4 v = ((const float4*)h1)[i];
    ushort4 o;
    o.x = f2bf(eluf(g[c0 + 0] * v.x + b[c0 + 0]));
    o.y = f2bf(eluf(g[c0 + 1] * v.y + b[c0 + 1]));
    o.z = f2bf(eluf(g[c0 + 2] * v.z + b[c0 + 2]));
    o.w = f2bf(eluf(g[c0 + 3] * v.w + b[c0 + 3]));
    ((ushort4*)h1b)[i] = o;
}

// ---------------------------------------------------------------- MFMA GEMM
// C[M x ldc](bf16) = A[M x K](bf16) @ BT[N_pad x K](bf16)^T
// 128x128 block tile, 4 waves 2x2, 64x64 wave tile of 32x32 MFMAs, BK=64.
// R4->R5: epilogue stores bf16 (only consumers are the gather kernels).
#define MBM 128
#define MBN 128
#define MBK 64
__global__ __launch_bounds__(256) void k_mgemm(
    const ushort_t* __restrict__ A, const ushort_t* __restrict__ BT,
    ushort_t* __restrict__ C, int M, int K, int N, int ldc)
{
    __shared__ __align__(16) ushort_t Al[MBM * MBK];   // 16 KB
    __shared__ __align__(16) ushort_t Bl[MBN * MBK];   // 16 KB
    const int t = threadIdx.x;
    const int w = t >> 6, L = t & 63;
    const int i0 = blockIdx.x * MBM;
    const int j0 = blockIdx.y * MBN;
    const int wm = (w >> 1) * 64, wn = (w & 1) * 64;
    const int l31 = L & 31, half = L >> 5;

    int sm[4], sca[4];
    #pragma unroll
    for (int r = 0; r < 4; r++) {
        int s = (r * 4 + w) * 64 + L;      // chunk slot 0..1023
        int m = s >> 3;
        sm[r] = m;
        sca[r] = (s & 7) ^ (m & 7);
    }

    f32x16 acc[2][2];
    #pragma unroll
    for (int a = 0; a < 2; a++)
        #pragma unroll
        for (int b = 0; b < 2; b++)
            #pragma unroll
            for (int r = 0; r < 16; r++) acc[a][b][r] = 0.f;

    for (int kt = 0; kt < K; kt += MBK) {
        short8 sa[4], sb[4];
        #pragma unroll
        for (int r = 0; r < 4; r++) {
            int row = i0 + sm[r]; if (row >= M) row = M - 1;
            sa[r] = *(const short8*)&A[(size_t)row * K + kt + sca[r] * 8];
            sb[r] = *(const short8*)&BT[(size_t)(j0 + sm[r]) * K + kt + sca[r] * 8];
        }
        __syncthreads();
        #pragma unroll
        for (int r = 0; r < 4; r++) {
            int s = (r * 4 + w) * 64 + L;
            *(short8*)&Al[s * 8] = sa[r];
            *(short8*)&Bl[s * 8] = sb[r];
        }
        __syncthreads();
        #pragma unroll
        for (int ks = 0; ks < 4; ks++) {
            short8 af[2], bfr[2];
            #pragma unroll
            for (int mt = 0; mt < 2; mt++) {
                int m = wm + mt * 32 + l31;
                int c = (ks * 2 + half) ^ (m & 7);
                af[mt] = *(const short8*)&Al[(m * 8 + c) * 8];
            }
            #pragma unroll
            for (int nt = 0; nt < 2; nt++) {
                int n = wn + nt * 32 + l31;
                int c = (ks * 2 + half) ^ (n & 7);
                bfr[nt] = *(const short8*)&Bl[(n * 8 + c) * 8];
            }
            #pragma unroll
            for (int mt = 0; mt < 2; mt++)
                #pragma unroll
                for (int nt = 0; nt < 2; nt++)
                    acc[mt][nt] = __builtin_amdgcn_mfma_f32_32x32x16_bf16(
                        af[mt], bfr[nt], acc[mt][nt], 0, 0, 0);
        }
    }
    #pragma unroll
    for (int mt = 0; mt < 2; mt++)
        #pragma unroll
        for (int nt = 0; nt < 2; nt++) {
            int col = j0 + wn + nt * 32 + l31;
            int rbase = i0 + wm + mt * 32 + 4 * half;
            if (col < N) {
                #pragma unroll
                for (int r = 0; r < 16; r++) {
                    int row = rbase + (r & 3) + 8 * (r >> 2);
                    if (row < M) C[(size_t)row * ldc + col] = f2bf(acc[mt][nt][r]);
                }
            }
        }
}

// ---------------------------------------------------------------- layer-1 node kernel
// One block (4 waves, wave h = head h) per dst node; bf16 payload.
// Logit pass: thread (qe=lane>>2, qq=lane&3) dots 16 ch of edge qe (2 b128).
// Aggregation: thread (es=lane>>4, q=lane&15) owns channels h*64+q*4..+3 and
// edges {es,4+es,8+es,12+es} (4 ds_read_b64), cross-group reduce at the end.
// Invalid edges are zero-filled at staging; p=exp(-inf)=0 masks them.
#define CH1 16
#define XRS 264   // padded LDS row stride in ushorts (16B-aligned)
__global__ __launch_bounds__(256) void k_node1(
    const ushort_t* __restrict__ xlr, const int* __restrict__ row_start,
    const int* __restrict__ csr_src, const float* __restrict__ att1,
    const float* __restrict__ b1, float* __restrict__ h1)
{
    __shared__ __align__(16) ushort_t xl_sh[CH1 * XRS];   // 8448 B
    __shared__ __align__(16) float xr_sh[D1];
    __shared__ __align__(16) float att_sh[D1];
    __shared__ __align__(16) float p_sh[HEADS][CH1];
    __shared__ int src_sh[CH1];
    const int i = blockIdx.x;
    const int t = threadIdx.x;
    const int h = t >> 6, lane = t & 63;
    const int qe = lane >> 2, qq = lane & 3;       // logit mapping
    const int es = lane >> 4, q = lane & 15;       // aggregation mapping
    const int half = lane >> 5, l31 = lane & 31;   // staging mapping
    const int s0 = row_start[i], s1 = row_start[i + 1];
    xr_sh[t] = bf2f(xlr[(size_t)i * 512 + 256 + t]);
    att_sh[t] = att1[t];
    const float4 bvv = *(const float4*)&b1[h * 64 + q * 4];
    __syncthreads();

    float xr_t[16], at_t[16];
    {
        const float* xrp = &xr_sh[h * 64 + qq * 16];
        const float* atp = &att_sh[h * 64 + qq * 16];
        #pragma unroll
        for (int k = 0; k < 16; k += 4) {
            float4 a = *(const float4*)&xrp[k];
            float4 b = *(const float4*)&atp[k];
            xr_t[k + 0] = a.x; xr_t[k + 1] = a.y; xr_t[k + 2] = a.z; xr_t[k + 3] = a.w;
            at_t[k + 0] = b.x; at_t[k + 1] = b.y; at_t[k + 2] = b.z; at_t[k + 3] = b.w;
        }
    }

    float acc4[4] = {0.f, 0.f, 0.f, 0.f};
    float m_run = -__builtin_inff(), l_run = 0.f;

    for (int base = s0; base < s1; base += CH1) {
        const int cnt = min(CH1, s1 - base);
        __syncthreads();                       // prev chunk reads done
        if (t < cnt) src_sh[t] = csr_src[base + t];
        __syncthreads();
        // stage: half-wave per edge, 32 lanes x 16B = 512B row (xl part)
        #pragma unroll
        for (int r = 0; r < 2; r++) {
            int e = r * 8 + h * 2 + half;
            if (e < cnt) {
                short8 v = *(const short8*)&xlr[(size_t)src_sh[e] * 512 + l31 * 8];
                *(short8*)&xl_sh[e * XRS + l31 * 8] = v;
            } else {
                short8 z = {0, 0, 0, 0, 0, 0, 0, 0};
                *(short8*)&xl_sh[e * XRS + l31 * 8] = z;
            }
        }
        __syncthreads();
        // logit: edge qe, channels h*64 + qq*16 .. +15
        float dot = 0.f;
        {
            const ushort_t* xp = &xl_sh[qe * XRS + h * 64 + qq * 16];
            short8 u0 = *(const short8*)&xp[0];
            short8 u1 = *(const short8*)&xp[8];
            #pragma unroll
            for (int k = 0; k < 8; k++) {
                float v0 = bf2f((ushort_t)u0[k]);
                float v1 = bf2f((ushort_t)u1[k]);
                dot += lrelu(v0 + xr_t[k]) * at_t[k];
                dot += lrelu(v1 + xr_t[8 + k]) * at_t[8 + k];
            }
        }
        dot += __shfl_xor(dot, 1, 64);
        dot += __shfl_xor(dot, 2, 64);
        if (qq == 0) p_sh[h][qe] = (qe < cnt) ? dot : -__builtin_inff();
        // wave-local write->read (compiler inserts lgkmcnt wait)
        float4 L0 = *(const float4*)&p_sh[h][0];
        float4 L1 = *(const float4*)&p_sh[h][4];
        float4 L2 = *(const float4*)&p_sh[h][8];
        float4 L3 = *(const float4*)&p_sh[h][12];
        float lg[16] = {L0.x, L0.y, L0.z, L0.w, L1.x, L1.y, L1.z, L1.w,
                        L2.x, L2.y, L2.z, L2.w, L3.x, L3.y, L3.z, L3.w};
        float m_chunk = lg[0];
        #pragma unroll
        for (int e = 1; e < 16; e++) m_chunk = fmaxf(m_chunk, lg[e]);
        const float m_new = fmaxf(m_run, m_chunk);
        const float scale = __expf(m_run - m_new);   // exp(-inf)=0 first time
        float pr[4];
        float lsum = 0.f;
        #pragma unroll
        for (int r = 0; r < 4; r++) {      // only this group's 4 edges
            pr[r] = __expf(lg[r * 4 + es] - m_new);
            lsum += pr[r];
        }
        lsum += __shfl_xor(lsum, 16, 64);
        lsum += __shfl_xor(lsum, 32, 64);
        #pragma unroll
        for (int j = 0; j < 4; j++) acc4[j] *= scale;
        l_run = l_run * scale + lsum;
        m_run = m_new;
        // aggregation: 4 edges x 4 channels, zero-filled rows need no mask
        #pragma unroll
        for (int r = 0; r < 4; r++) {
            int e = r * 4 + es;
            const ushort_t* ap = &xl_sh[e * XRS + h * 64 + q * 4];
            ushort4 u = *(const ushort4*)ap;
            acc4[0] += pr[r] * bf2f(u.x);
            acc4[1] += pr[r] * bf2f(u.y);
            acc4[2] += pr[r] * bf2f(u.z);
            acc4[3] += pr[r] * bf2f(u.w);
        }
    }
    // reduce the 4 es-groups (butterfly -> all lanes hold total)
    #pragma unroll
    for (int j = 0; j < 4; j++) {
        acc4[j] += __shfl_xor(acc4[j], 16, 64);
        acc4[j] += __shfl_xor(acc4[j], 32, 64);
    }
    const float inv = 1.f / (l_run + SM_EPS);
    if (lane < 16) {
        float4 o = make_float4(acc4[0] * inv + bvv.x, acc4[1] * inv + bvv.y,
                               acc4[2] * inv + bvv.z, acc4[3] * inv + bvv.w);
        *(float4*)&h1[(size_t)i * 256 + h * 64 + q * 4] = o;
    }
}

// ---------------------------------------------------------------- batchnorm
__global__ void k_bnstats(const float* __restrict__ h1, float* __restrict__ bn_sum,
                          float* __restrict__ bn_sumsq) {
    const int t = threadIdx.x;
    const int rows_per = (N_NODES + gridDim.x - 1) / gridDim.x;
    const int r0 = blockIdx.x * rows_per;
    const int r1 = min(N_NODES, r0 + rows_per);
    float s = 0.f, s2 = 0.f;
    for (int r = r0; r < r1; r++) {
        float v = h1[(size_t)r * 256 + t];
        s += v; s2 += v * v;
    }
    atomicAdd(&bn_sum[t], s);
    atomicAdd(&bn_sumsq[t], s2);
}

__global__ void k_bnfinal(const float* __restrict__ bn_sum, const float* __restrict__ bn_sumsq,
                          const float* __restrict__ gamma, const float* __restrict__ beta,
                          float* __restrict__ bn_g, float* __restrict__ bn_b) {
    const int t = threadIdx.x;
    float mean = bn_sum[t] * (1.f / N_NODES);
    float var = bn_sumsq[t] * (1.f / N_NODES) - mean * mean;
    float g = gamma[t] * rsqrtf(var + BN_EPS);
    bn_g[t] = g;
    bn_b[t] = beta[t] - g * mean;
}

// ---------------------------------------------------------------- layer-2 node kernel
__global__ __launch_bounds__(256) void k_node2(
    const ushort_t* __restrict__ xlr2, const int* __restrict__ row_start,
    const int* __restrict__ csr_src, const float* __restrict__ att2,
    const float* __restrict__ b2, float* __restrict__ out)
{
    const int wv = threadIdx.x >> 6, lane = threadIdx.x & 63;
    const int i = blockIdx.x * 4 + wv;
    if (i >= N_NODES) return;
    const int s0 = row_start[i], s1 = row_start[i + 1];
    const bool act = lane < NCLS;
    const float xr = act ? bf2f(xlr2[(size_t)i * 80 + 40 + lane]) : 0.f;
    const float att = act ? att2[lane] : 0.f;
    float m_run = -__builtin_inff(), l_run = 0.f, acc = 0.f;
    for (int e = s0; e < s1; e++) {
        int src = csr_src[e];
        float xl = act ? bf2f(xlr2[(size_t)src * 80 + lane]) : 0.f;
        float v = lrelu(xl + xr) * att;
        #pragma unroll
        for (int off = 32; off; off >>= 1) v += __shfl_xor(v, off, 64);
        float m_new = fmaxf(m_run, v);
        float sc = __expf(m_run - m_new);
        float p = __expf(v - m_new);
        acc = acc * sc + p * xl;
        l_run = l_run * sc + p;
        m_run = m_new;
    }
    if (act) out[(size_t)i * 40 + lane] = acc / (l_run + SM_EPS) + b2[lane];
}

// ---------------------------------------------------------------- launch
static inline size_t align_up(size_t v, size_t a) { return (v + a - 1) & ~(a - 1); }

extern "C" void kernel_launch(void* const* d_in, const int* in_sizes, int n_in,
                              void* d_out, int out_size, void* d_ws, size_t ws_size,
                              hipStream_t stream)
{
    const float* x     = (const float*)d_in[0];
    const int*   ei    = (const int*)d_in[1];
    const float* Wl1   = (const float*)d_in[2];
    const float* Wr1   = (const float*)d_in[3];
    const float* att1  = (const float*)d_in[4];
    const float* b1    = (const float*)d_in[5];
    const float* gamma1= (const float*)d_in[6];
    const float* beta1 = (const float*)d_in[7];
    const float* Wl2   = (const float*)d_in[8];
    const float* Wr2   = (const float*)d_in[9];
    const float* att2  = (const float*)d_in[10];
    const float* b2    = (const float*)d_in[11];
    float* out = (float*)d_out;

    char* ws = (char*)d_ws;
    size_t off = 0;
    ushort_t* xlr1b = (ushort_t*)(ws + off); off += (size_t)N_NODES * 512 * 2; // 51.2 MB
    float*    h1    = (float*)   (ws + off); off += (size_t)N_NODES * 256 * 4; // 51.2 MB
    ushort_t* h1b   = (ushort_t*)(ws + off); off += (size_t)N_NODES * 256 * 2; // 25.6 MB
    int*   csr_src = (int*)  (ws + off); off += align_up((size_t)ET * 4, 256);
    int*   row_st  = (int*)  (ws + off); off += align_up((size_t)(N_NODES + 1) * 4, 256);
    int*   cursor  = (int*)  (ws + off); off += align_up((size_t)N_NODES * 4, 256);
    int*   deg     = (int*)  (ws + off); off += align_up((size_t)N_NODES * 4, 256);
    float* bn_sum  = (float*)(ws + off); off += 256 * 4;
    float* bn_sumsq= (float*)(ws + off); off += 256 * 4;
    float* bn_g    = (float*)(ws + off); off += 256 * 4;
    float* bn_b    = (float*)(ws + off); off += 256 * 4;
    ushort_t* BT1  = (ushort_t*)(ws + off); off += align_up((size_t)512 * 128 * 2, 256);
    ushort_t* BT2  = (ushort_t*)(ws + off); off += align_up((size_t)128 * 256 * 2, 256);
    // overlapped scratch (stream-ordered lifetimes):
    ushort_t* xlr2b = xlr1b;            // 8 MB, written after xlr1b is dead
    ushort_t* xb    = (ushort_t*)h1;    // 12.8 MB, dead before k_node1 writes h1

    hipMemsetAsync(deg, 0, (size_t)N_NODES * 4, stream);
    hipMemsetAsync(bn_sum, 0, 512 * 4, stream);   // bn_sum + bn_sumsq contiguous

    k_deg<<<(ET + 255) / 256, 256, 0, stream>>>(ei, deg);
    k_scan<<<1, 1024, 0, stream>>>(deg, row_st, cursor);
    k_scatter<<<(ET + 255) / 256, 256, 0, stream>>>(ei, cursor, csr_src);

    k_cvt_x<<<(N_NODES * IN_DIM / 4 + 255) / 256, 256, 0, stream>>>(x, xb, N_NODES * IN_DIM / 4);
    k_cvt_w1<<<512, 128, 0, stream>>>(Wl1, Wr1, BT1);
    k_cvt_w2<<<128, 256, 0, stream>>>(Wl2, Wr2, BT2);

    dim3 g1((N_NODES + MBM - 1) / MBM, 512 / MBN);
    k_mgemm<<<g1, 256, 0, stream>>>(xb, BT1, xlr1b, N_NODES, IN_DIM, 512, 512);
    k_node1<<<N_NODES, 256, 0, stream>>>(xlr1b, row_st, csr_src, att1, b1, h1);

    k_bnstats<<<250, 256, 0, stream>>>(h1, bn_sum, bn_sumsq);
    k_bnfinal<<<1, 256, 0, stream>>>(bn_sum, bn_sumsq, gamma1, beta1, bn_g, bn_b);
    k_cvt_h<<<(N_NODES * 256 / 4 + 255) / 256, 256, 0, stream>>>(h1, bn_g, bn_b, h1b);

    dim3 g2((N_NODES + MBM - 1) / MBM, 1);
    k_mgemm<<<g2, 256, 0, stream>>>(h1b, BT2, xlr2b, N_NODES, D1, 80, 80);
    k_node2<<<(N_NODES + 3) / 4, 256, 0, stream>>>(xlr2b, row_st, csr_src, att2, b2, out);
}